// Round 3
// baseline (438.377 us; speedup 1.0000x reference)
//
#include <hip/hip_runtime.h>

// Problem constants (B,N,T,D) = (8,256,64,512)
#define Bb 8
#define Nn 256
#define Tt 64
#define Dd 512
#define NT (Nn * Tt)   // 16384

// d_out layout (all float32, concatenated in return order):
//   new_x      : Bb*NT*Dd = 67,108,864
//   new_mask   : Bb*NT    = 131,072
//   doc_seq_len: Bb       = 8
//   new_tag    : Bb*NT    = 131,072
#define O_MASK (Bb * NT * Dd)
#define O_DOC  (O_MASK + Bb * NT)
#define O_TAG  (O_DOC + Bb)

// ws layout: int offsets[Bb][Nn+1]
#define WS_OFF_INTS (Bb * (Nn + 1))

typedef float f4 __attribute__((ext_vector_type(4)));  // native vector: OK for nontemporal builtins

// ---------------------------------------------------------------------------
// Kernel 1: per-batch exclusive scan of length[] (Nn=256, 1 block/batch).
// ---------------------------------------------------------------------------
__global__ __launch_bounds__(Nn) void scan_kernel(const int* __restrict__ length,
                                                  int* __restrict__ ws_off,
                                                  float* __restrict__ out_doc) {
    __shared__ int s[Nn];
    const int b = blockIdx.x;
    const int tid = threadIdx.x;
    const int v = length[b * Nn + tid];
    s[tid] = v;
    __syncthreads();
    for (int off = 1; off < Nn; off <<= 1) {
        int t = 0;
        if (tid >= off) t = s[tid - off];
        __syncthreads();
        if (tid >= off) s[tid] += t;
        __syncthreads();
    }
    ws_off[b * (Nn + 1) + tid] = s[tid] - v;   // exclusive prefix
    if (tid == Nn - 1) {
        ws_off[b * (Nn + 1) + Nn] = s[Nn - 1]; // total = doc_seq_len
        out_doc[b] = (float)s[Nn - 1];
    }
}

// ---------------------------------------------------------------------------
// Kernel 2 (fused map+add): 2 output rows per 256-thread block.
// Leader lanes (tid 0,1) binary-search the L2-resident offset table for their
// row's source segment, write new_mask/new_tag, publish src via LDS.
// All threads then stream: out = gcn[node] (+ x[src] if valid), float4 lanes.
// ---------------------------------------------------------------------------
__global__ __launch_bounds__(256) void fused_kernel(const f4* __restrict__ x,
                                                    const f4* __restrict__ gcn,
                                                    const int* __restrict__ tags,
                                                    const int* __restrict__ ws_off,
                                                    float* __restrict__ out_mask,
                                                    float* __restrict__ out_tag,
                                                    f4* __restrict__ out) {
    __shared__ int s_src[2];
    const int tid  = threadIdx.x;
    const int row0 = blockIdx.x << 1;           // first of 2 rows

    if (tid < 2) {
        const int row = row0 + tid;
        const int b   = row >> 14;              // / NT
        const int j   = row & (NT - 1);
        const int* off = ws_off + b * (Nn + 1);
        const int doc = off[Nn];
        int   src = -1;
        float m = 0.0f, tg = 0.0f;              // PAD_TAG = 0
        if (j < doc) {
            int lo = 0, hi = Nn - 1;
            #pragma unroll
            for (int it = 0; it < 8; ++it) {    // 2^8 = 256 segments
                int mid = (lo + hi + 1) >> 1;
                if (off[mid] <= j) lo = mid; else hi = mid - 1;
            }
            src = lo * Tt + (j - off[lo]);
            m  = 1.0f;
            tg = (float)tags[b * NT + src];
        }
        s_src[tid]    = src;
        out_mask[row] = m;
        out_tag[row]  = tg;
    }
    __syncthreads();

    const int half = tid >> 7;                  // which of the 2 rows
    const int c    = tid & 127;                 // float4 column (D/4 = 128)
    const int row  = row0 + half;
    const int b    = row >> 14;
    const int node = (row & (NT - 1)) >> 6;     // / Tt

    f4 v = gcn[(b * Nn + node) * 128 + c];
    const int src = s_src[half];
    if (src >= 0) {
        const f4 xv = __builtin_nontemporal_load(&x[((b << 14) + src) * 128 + c]);
        v += xv;
    }
    // out index row*128+c == blockIdx.x*256+tid — fully contiguous store
    __builtin_nontemporal_store(v, &out[row * 128 + c]);
}

extern "C" void kernel_launch(void* const* d_in, const int* in_sizes, int n_in,
                              void* d_out, int out_size, void* d_ws, size_t ws_size,
                              hipStream_t stream) {
    const float* x     = (const float*)d_in[0];  // (B,N,T,D)
    const float* x_gcn = (const float*)d_in[1];  // (B,N,D)
    // d_in[2] = mask — unused (prefix mask fully determined by length)
    const int* length  = (const int*)d_in[3];    // (B,N)
    const int* tags    = (const int*)d_in[4];    // (B,N,T)

    float* out    = (float*)d_out;
    int*   ws_off = (int*)d_ws;

    scan_kernel<<<Bb, Nn, 0, stream>>>(length, ws_off, out + O_DOC);
    fused_kernel<<<(Bb * NT) / 2, 256, 0, stream>>>(
        (const f4*)x, (const f4*)x_gcn, tags, ws_off,
        out + O_MASK, out + O_TAG, (f4*)out);
}